// Round 9
// baseline (217.889 us; speedup 1.0000x reference)
//
#include <hip/hip_runtime.h>
#include <math.h>

#define B_    4
#define CIN_  128
#define COUT_ 128
#define H_    128
#define W_    128
#define HW_   (H_*W_)
#define KK_   9

typedef __attribute__((ext_vector_type(4))) float f32x4;
typedef _Float16 h8 __attribute__((ext_vector_type(8)));
typedef float f2v __attribute__((ext_vector_type(2), aligned(4)));  // 4B-aligned pair load

static __device__ __forceinline__ unsigned short f2h(float f) {
    union { _Float16 h; unsigned short u; } v; v.h = (_Float16)f;
    return v.u;
}

// K-chunk order (both GEMMs): q = cblock*9 + tap (channel-outer, tap inner).

// ---------------------------------------------------------------------------
// Prep (fused): bx<1024 -> transpose {inp,feat} NCHW f32 -> NHWC f16;
//               bx<1096 -> w_dc swizzle (f16); else -> w_off swizzle (f16).
// ---------------------------------------------------------------------------
__global__ __launch_bounds__(256) void prep_kernel(
    const float* __restrict__ inp, const float* __restrict__ feat,
    const float* __restrict__ w_dc, const float* __restrict__ w_off,
    unsigned short* __restrict__ inpT, unsigned short* __restrict__ featT,
    unsigned short* __restrict__ w_swz, unsigned short* __restrict__ woff_swz)
{
    const int bx = blockIdx.x;
    const int tid = threadIdx.x;
    __shared__ unsigned short s_T[128 * 142];   // 36352 B (tpose branch only)

    if (bx < 1024) {
        // ---- transpose: block = (src, b, y); LDS tile [128x][142c] ----
        const int bi = bx & 511;
        const int b = bi >> 7, y = bi & 127;
        const float* src = (bx < 512 ? inp : feat) + (size_t)b * CIN_ * HW_ + y * W_;
        unsigned short* dstb = (bx < 512 ? inpT : featT) + (size_t)bi * (W_ * CIN_);
        const int xs = (tid & 63) * 2;
        const int c0 = tid >> 6;
#pragma unroll 4
        for (int p = 0; p < 32; ++p) {
            int c = c0 + 4 * p;
            f2v d = *(const f2v*)(src + (size_t)c * HW_ + xs);
            s_T[xs * 142 + c]       = f2h(d.x);
            s_T[(xs + 1) * 142 + c] = f2h(d.y);
        }
        __syncthreads();
        const int cs = (tid & 15) * 8;
        const int x0 = tid >> 4;
#pragma unroll
        for (int p = 0; p < 8; ++p) {
            int x = x0 + 16 * p;
            unsigned r[4];
#pragma unroll
            for (int j = 0; j < 4; ++j) {
                unsigned lo = s_T[x * 142 + cs + 2 * j];
                unsigned hi = s_T[x * 142 + cs + 2 * j + 1];
                r[j] = lo | (hi << 16);
            }
            *(int4*)(dstb + (size_t)x * CIN_ + cs) = make_int4(r[0], r[1], r[2], r[3]);
        }
    } else if (bx < 1096) {
        // ---- w_dc swizzle -> f16 A-fragments ----
        int idx = (bx - 1024) * 256 + tid;   // [0, 36*8*64)
        int q   = idx >> 9;
        int rem = idx & 511;
        int ocb = rem >> 6;
        int l   = rem & 63;
        int cbq = q / 9;
        int k   = q - cbq * 9;
        int cb  = (cbq << 5) + ((l >> 4) << 3);
        int oc  = (ocb << 4) + (l & 15);
        unsigned r[4];
#pragma unroll
        for (int j = 0; j < 4; ++j) {
            float f0 = w_dc[((size_t)(oc * CIN_ + cb + 2 * j    )) * KK_ + k];
            float f1 = w_dc[((size_t)(oc * CIN_ + cb + 2 * j + 1)) * KK_ + k];
            r[j] = (unsigned)f2h(f0) | ((unsigned)f2h(f1) << 16);
        }
        *(int4*)&w_swz[(size_t)idx * 8] = make_int4(r[0], r[1], r[2], r[3]);
    } else {
        // ---- w_off swizzle -> f16 A-fragments, oc padded 27->32 ----
        int idx = (bx - 1096) * 256 + tid;   // [0, 36*2*64)
        int q   = idx >> 7;
        int rem = idx & 127;
        int l   = rem & 63;
        int cbq = q / 9;
        int k   = q - cbq * 9;
        int cb  = (cbq << 5) + ((l >> 4) << 3);
        int oc  = ((rem >> 6) << 4) + (l & 15);
        unsigned r[4];
#pragma unroll
        for (int j = 0; j < 4; ++j) {
            float f0 = 0.f, f1 = 0.f;
            if (oc < 27) {
                f0 = w_off[((size_t)(oc * CIN_ + cb + 2 * j    )) * KK_ + k];
                f1 = w_off[((size_t)(oc * CIN_ + cb + 2 * j + 1)) * KK_ + k];
            }
            r[j] = (unsigned)f2h(f0) | ((unsigned)f2h(f1) << 16);
        }
        *(int4*)&woff_swz[(size_t)idx * 8] = make_int4(r[0], r[1], r[2], r[3]);
    }
}

// ---------------------------------------------------------------------------
// Fused main (v8):
// Phase 1: offset conv from featT (NHWC f16), LDS halo tile, f16 MFMA
//   (unchanged from v7).
// Phase 2: deformable conv, REGISTER-DIRECT B-fragments — each wave owns a
//   16-px quarter and ALL 128 oc. Lane (kg=lane>>4, pn=lane&15) gathers
//   exactly its own B-fragment: px = wave*16+pn, ch kg*8 (+cb*32). Same
//   64B-line coalescing as v7 (lanes {pn,16+pn,32+pn,48+pn} share a line,
//   16 lines/instr), zero redundancy (waves own disjoint px) — and the
//   entire s_V round-trip, lgkm drain, and ALL 36 main-loop barriers are
//   gone. Per chunk/wave: 4 gathers + pk-f16 combine -> B-frag in reg,
//   8 A-frag loads (L2-hot w_swz), 8 MFMA into acc[8]. Waves fully
//   independent -> latency hidden by 16 unsynced waves/CU.
// ---------------------------------------------------------------------------
__global__ __launch_bounds__(256, 4) void fused_kernel(
    const unsigned short* __restrict__ featT, const unsigned short* __restrict__ inpT,
    const unsigned short* __restrict__ woff_swz, const unsigned short* __restrict__ w_swz,
    const float* __restrict__ b_off, const float* __restrict__ b_dc,
    float* __restrict__ out)
{
    const int tid = threadIdx.x;
    const int bx = blockIdx.x;
    const int lidx = ((bx & 7) << 7) | (bx >> 3);   // XCD swizzle, 1024 blocks
    const int b  = lidx >> 8;
    const int h  = (lidx & 255) >> 1;
    const int w0 = (lidx & 1) << 6;                 // == pw0

    __shared__ __align__(16) unsigned short s_R0[7936];   // 15872B: s_F (phase 1)
    __shared__ float  offv[27][65];                       // 7020B
    __shared__ int2   s_midx[576];                        // 4608B
    __shared__ float4 s_mwgt[576];                        // 9216B

    unsigned short (*s_F)[66][40] = (unsigned short (*)[66][40])s_R0;

    const int lane = tid & 63;
    const int wave = tid >> 6;
    const int kg = lane >> 4, pn = lane & 15;

    // ================= phase 1: offset conv (f16 MFMA, featT staging) =======
    {
        const unsigned short* fT = featT;   // [b][y][x][c] f16
        f32x4 acc[2];
        acc[0] = (f32x4){0.f, 0.f, 0.f, 0.f};
        acc[1] = (f32x4){0.f, 0.f, 0.f, 0.f};

        const int me = tid >> 2;      // main px 0..63 (tile-x me+1)
        const int mg = tid & 3;       // ch-group of 8

        for (int cb = 0; cb < 4; ++cb) {
            if (cb) __syncthreads();       // taps of cb-1 done reading s_F

            // main tile: 3 rows x 64 px x 32 ch, one h8 copy per thread per row
#pragma unroll
            for (int r = 0; r < 3; ++r) {
                int y = h + r - 1;
                h8 d{};
                if ((unsigned)y < (unsigned)H_)
                    d = *(const h8*)(fT + (((size_t)(b * H_ + y) * W_ + (w0 + me)) * CIN_
                                           + (cb << 5) + (mg << 3)));
                *(h8*)&s_F[r][me + 1][mg << 3] = d;
            }
            // halo px: tile-x 0 (x=w0-1) and 65 (x=w0+64), 24 items
            if (tid < 24) {
                int r = tid >> 3, side = (tid >> 2) & 1, g = tid & 3;
                int x = side ? (w0 + 64) : (w0 - 1);
                int t = side ? 65 : 0;
                int y = h + r - 1;
                h8 d{};
                if (((unsigned)y < (unsigned)H_) & ((unsigned)x < (unsigned)W_))
                    d = *(const h8*)(fT + (((size_t)(b * H_ + y) * W_ + x) * CIN_
                                           + (cb << 5) + (g << 3)));
                *(h8*)&s_F[r][t][g << 3] = d;
            }
            __syncthreads();

            const int qb2 = cb * 18;
            const h8* wb = (const h8*)woff_swz;
            h8 a0 = wb[(size_t)(qb2    ) * 64 + lane];
            h8 a1 = wb[(size_t)(qb2 + 1) * 64 + lane];
#pragma unroll
            for (int k = 0; k < 9; ++k) {
                const int ky = k / 3, kx = k - 3 * ky;
                h8 bfr = *(const h8*)&s_F[ky][wave * 16 + pn + kx][kg * 8];
                h8 na0, na1;
                if (k < 8) {
                    na0 = wb[(size_t)(qb2 + 2 * k + 2) * 64 + lane];
                    na1 = wb[(size_t)(qb2 + 2 * k + 3) * 64 + lane];
                }
                acc[0] = __builtin_amdgcn_mfma_f32_16x16x32_f16(a0, bfr, acc[0], 0, 0, 0);
                acc[1] = __builtin_amdgcn_mfma_f32_16x16x32_f16(a1, bfr, acc[1], 0, 0, 0);
                if (k < 8) { a0 = na0; a1 = na1; }
            }
        }

        // epilogue -> offv (LDS, f32)
        const int row0 = kg << 2;
        const int pwl  = wave * 16 + pn;
#pragma unroll
        for (int mt = 0; mt < 2; ++mt) {
#pragma unroll
            for (int i = 0; i < 4; ++i) {
                int oc = mt * 16 + row0 + i;
                if (oc < 27) {
                    float v = acc[mt][i] + b_off[oc];
                    if (oc >= 18) v = 1.f / (1.f + __expf(-v));
                    offv[oc][pwl] = v;
                }
            }
        }
    }
    __syncthreads();   // offv visible to all

    // ================= bilinear metadata: 9 taps x 64 px =================
    for (int i = tid; i < 576; i += 256) {
        int k = i >> 6, p = i & 63;
        int ky = k / 3, kx = k - ky * 3;
        int pw = w0 + p;
        float offy = offv[2 * k    ][p];
        float offx = offv[2 * k + 1][p];
        float mask = offv[18 + k   ][p];
        float py  = offy + (float)(h  + ky - 1);
        float px_ = offx + (float)(pw + kx - 1);
        float y0f = floorf(py), x0f = floorf(px_);
        float ly = py - y0f, lx = px_ - x0f;
        int y0 = (int)y0f, x0 = (int)x0f;
        int y1 = y0 + 1;
        int hx = min(max(x0, 0), W_ - 2);
        float wlo = 0.f, whi = 0.f;
        if (x0 == hx)          { wlo = 1.f - lx; whi = lx; }     // normal
        else if (x0 == hx - 1) { wlo = lx; }                     // x0 == -1
        else if (x0 == hx + 1) { whi = 1.f - lx; }               // x0 == W-1
        float wt_top = ((unsigned)y0 < (unsigned)H_) ? (1.f - ly) * mask : 0.f;
        float wt_bot = ((unsigned)y1 < (unsigned)H_) ? ly * mask : 0.f;
        int cy0 = min(max(y0, 0), H_ - 1), cy1 = min(max(y1, 0), H_ - 1);
        s_midx[i] = make_int2(cy0 * W_ + hx, cy1 * W_ + hx);
        s_mwgt[i] = make_float4(wt_top * wlo, wt_top * whi,
                                wt_bot * wlo, wt_bot * whi);
    }
    __syncthreads();   // meta visible (last barrier in the kernel)

    // ========== phase 2: deformable conv, register-direct B-frags ==========
    const int p = wave * 16 + pn;         // this lane's pixel (0..63)
    const char* inpTb = (const char*)(inpT + (size_t)b * CIN_ * HW_);

    f32x4 acc2[8];
#pragma unroll
    for (int m = 0; m < 8; ++m) acc2[m] = (f32x4){0.f, 0.f, 0.f, 0.f};

    h8 pf0, pf1, pf2, pf3;   // corners: (y0,x0),(y0,x1),(y1,x0),(y1,x1)

    auto issue = [&](int qq) {
        int cbq = qq / 9;
        int k   = qq - cbq * 9;
        int2 id = s_midx[(k << 6) + p];
        int coff = (cbq << 6) + (kg << 4);   // byte: (cbq*32 + kg*8) f16
        const char* g0 = inpTb + ((size_t)(unsigned)id.x << 8) + coff;
        const char* g1 = inpTb + ((size_t)(unsigned)id.y << 8) + coff;
        pf0 = *(const h8*)(g0);
        pf1 = *(const h8*)(g0 + 256);     // x+1: +CIN_*2B
        pf2 = *(const h8*)(g1);
        pf3 = *(const h8*)(g1 + 256);
    };

    issue(0);

    for (int q = 0; q < 36; ++q) {
        int k = q - (q / 9) * 9;

        // combine prefetched corners -> this lane's B-fragment (pk-f16)
        float4 wt = s_mwgt[(k << 6) + p];
        h8 v = pf0 * (_Float16)wt.x;
        v += pf1 * (_Float16)wt.y;
        v += pf2 * (_Float16)wt.z;
        v += pf3 * (_Float16)wt.w;

        int qn = (q + 1 < 36) ? q + 1 : 35;
        issue(qn);                         // next-chunk gathers in flight

        const h8* wp = (const h8*)w_swz + (size_t)(q * 8) * 64 + lane;
#pragma unroll
        for (int m = 0; m < 8; ++m) {
            h8 af = wp[(size_t)m * 64];
            acc2[m] = __builtin_amdgcn_mfma_f32_16x16x32_f16(af, v, acc2[m], 0, 0, 0);
        }
    }

    // epilogue: D[row=oc_local][col=px_local]; col = pn, row = kg*4+i
    const int pw = w0 + wave * 16 + pn;
#pragma unroll
    for (int m = 0; m < 8; ++m) {
#pragma unroll
        for (int i = 0; i < 4; ++i) {
            int oc = m * 16 + (kg << 2) + i;
            out[((size_t)(b * COUT_ + oc)) * HW_ + h * W_ + pw] =
                acc2[m][i] + b_dc[oc];
        }
    }
}

extern "C" void kernel_launch(void* const* d_in, const int* in_sizes, int n_in,
                              void* d_out, int out_size, void* d_ws, size_t ws_size,
                              hipStream_t stream)
{
    const float* inp   = (const float*)d_in[0];
    const float* feat  = (const float*)d_in[1];
    const float* w_off = (const float*)d_in[2];
    const float* b_off = (const float*)d_in[3];
    const float* w_dc  = (const float*)d_in[4];
    const float* b_dc  = (const float*)d_in[5];
    float* out  = (float*)d_out;
    unsigned short* w_swz    = (unsigned short*)d_ws;                        // 288 KB (f16)
    unsigned short* woff_swz = (unsigned short*)((char*)d_ws + 294912);      // 72 KB (f16)
    unsigned short* inpT     = (unsigned short*)((char*)d_ws + 368640);      // 16 MB (f16 NHWC)
    unsigned short* featT    = (unsigned short*)((char*)d_ws + 368640 + 16777216);  // 16 MB

    prep_kernel<<<dim3(1114), dim3(256), 0, stream>>>(inp, feat, w_dc, w_off,
                                                      inpT, featT, w_swz, woff_swz);
    fused_kernel<<<dim3(1024), dim3(256), 0, stream>>>(featT, inpT, woff_swz, w_swz,
                                                       b_off, b_dc, out);
}

// Round 11
// 217.207 us; speedup vs baseline: 1.0031x; 1.0031x over previous
//
#include <hip/hip_runtime.h>
#include <math.h>

#define B_    4
#define CIN_  128
#define COUT_ 128
#define H_    128
#define W_    128
#define HW_   (H_*W_)
#define KK_   9

typedef __attribute__((ext_vector_type(4))) float f32x4;
typedef _Float16 h8 __attribute__((ext_vector_type(8)));
typedef float f2v __attribute__((ext_vector_type(2), aligned(4)));  // 4B-aligned pair load

static __device__ __forceinline__ unsigned short f2h(float f) {
    union { _Float16 h; unsigned short u; } v; v.h = (_Float16)f;
    return v.u;
}

// K-chunk order (both GEMMs): q = cblock*9 + tap (channel-outer, tap inner).

// ---------------------------------------------------------------------------
// Prep (fused): bx<1024 -> transpose {inp,feat} NCHW f32 -> NHWC f16;
//               bx<1096 -> w_dc swizzle (f16); else -> w_off swizzle (f16).
// ---------------------------------------------------------------------------
__global__ __launch_bounds__(256) void prep_kernel(
    const float* __restrict__ inp, const float* __restrict__ feat,
    const float* __restrict__ w_dc, const float* __restrict__ w_off,
    unsigned short* __restrict__ inpT, unsigned short* __restrict__ featT,
    unsigned short* __restrict__ w_swz, unsigned short* __restrict__ woff_swz)
{
    const int bx = blockIdx.x;
    const int tid = threadIdx.x;
    __shared__ unsigned short s_T[128 * 142];   // 36352 B (tpose branch only)

    if (bx < 1024) {
        // ---- transpose: block = (src, b, y); LDS tile [128x][142c] ----
        const int bi = bx & 511;
        const int b = bi >> 7, y = bi & 127;
        const float* src = (bx < 512 ? inp : feat) + (size_t)b * CIN_ * HW_ + y * W_;
        unsigned short* dstb = (bx < 512 ? inpT : featT) + (size_t)bi * (W_ * CIN_);
        const int xs = (tid & 63) * 2;
        const int c0 = tid >> 6;
#pragma unroll 4
        for (int p = 0; p < 32; ++p) {
            int c = c0 + 4 * p;
            f2v d = *(const f2v*)(src + (size_t)c * HW_ + xs);
            s_T[xs * 142 + c]       = f2h(d.x);
            s_T[(xs + 1) * 142 + c] = f2h(d.y);
        }
        __syncthreads();
        const int cs = (tid & 15) * 8;
        const int x0 = tid >> 4;
#pragma unroll
        for (int p = 0; p < 8; ++p) {
            int x = x0 + 16 * p;
            unsigned r[4];
#pragma unroll
            for (int j = 0; j < 4; ++j) {
                unsigned lo = s_T[x * 142 + cs + 2 * j];
                unsigned hi = s_T[x * 142 + cs + 2 * j + 1];
                r[j] = lo | (hi << 16);
            }
            *(int4*)(dstb + (size_t)x * CIN_ + cs) = make_int4(r[0], r[1], r[2], r[3]);
        }
    } else if (bx < 1096) {
        // ---- w_dc swizzle -> f16 A-fragments ----
        int idx = (bx - 1024) * 256 + tid;   // [0, 36*8*64)
        int q   = idx >> 9;
        int rem = idx & 511;
        int ocb = rem >> 6;
        int l   = rem & 63;
        int cbq = q / 9;
        int k   = q - cbq * 9;
        int cb  = (cbq << 5) + ((l >> 4) << 3);
        int oc  = (ocb << 4) + (l & 15);
        unsigned r[4];
#pragma unroll
        for (int j = 0; j < 4; ++j) {
            float f0 = w_dc[((size_t)(oc * CIN_ + cb + 2 * j    )) * KK_ + k];
            float f1 = w_dc[((size_t)(oc * CIN_ + cb + 2 * j + 1)) * KK_ + k];
            r[j] = (unsigned)f2h(f0) | ((unsigned)f2h(f1) << 16);
        }
        *(int4*)&w_swz[(size_t)idx * 8] = make_int4(r[0], r[1], r[2], r[3]);
    } else {
        // ---- w_off swizzle -> f16 A-fragments, oc padded 27->32 ----
        int idx = (bx - 1096) * 256 + tid;   // [0, 36*2*64)
        int q   = idx >> 7;
        int rem = idx & 127;
        int l   = rem & 63;
        int cbq = q / 9;
        int k   = q - cbq * 9;
        int cb  = (cbq << 5) + ((l >> 4) << 3);
        int oc  = ((rem >> 6) << 4) + (l & 15);
        unsigned r[4];
#pragma unroll
        for (int j = 0; j < 4; ++j) {
            float f0 = 0.f, f1 = 0.f;
            if (oc < 27) {
                f0 = w_off[((size_t)(oc * CIN_ + cb + 2 * j    )) * KK_ + k];
                f1 = w_off[((size_t)(oc * CIN_ + cb + 2 * j + 1)) * KK_ + k];
            }
            r[j] = (unsigned)f2h(f0) | ((unsigned)f2h(f1) << 16);
        }
        *(int4*)&woff_swz[(size_t)idx * 8] = make_int4(r[0], r[1], r[2], r[3]);
    }
}

// ---------------------------------------------------------------------------
// Fused main (v9):
// Phase 1: offset conv from featT (NHWC f16), LDS halo tile, f16 MFMA
//   (unchanged from v7/v8).
// Phase 2: deformable conv, register-direct B-frags (v8 structure: wave owns
//   16 px x all 128 oc; lane gathers exactly its own B-fragment; zero LDS
//   round-trip, zero main-loop barriers) + v9 FIX: A-fragments prefetched ONE
//   ITERATION AHEAD. v8's bug: A(q) loaded between gathers(q+1) and MFMAs(q)
//   forced vmcnt(0) per chunk (MFMA consumed the newest load), draining the
//   gather prefetch -> exposed scatter latency every chunk (MfmaUtil 8%).
//   v9 per-iter order: combine pf(q) [vmcnt(8), counted] -> issue gathers(q+1)
//   -> MFMAs on A(q) [vmcnt(4); A is L1-sequential, lands before the scatter
//   gathers it trails] -> load A(q+1) [dies into af before next iter; +32
//   VGPR peak only]. No wait in the loop ever drains the newest loads.
// ---------------------------------------------------------------------------
__global__ __launch_bounds__(256, 4) void fused_kernel(
    const unsigned short* __restrict__ featT, const unsigned short* __restrict__ inpT,
    const unsigned short* __restrict__ woff_swz, const unsigned short* __restrict__ w_swz,
    const float* __restrict__ b_off, const float* __restrict__ b_dc,
    float* __restrict__ out)
{
    const int tid = threadIdx.x;
    const int bx = blockIdx.x;
    const int lidx = ((bx & 7) << 7) | (bx >> 3);   // XCD swizzle, 1024 blocks
    const int b  = lidx >> 8;
    const int h  = (lidx & 255) >> 1;
    const int w0 = (lidx & 1) << 6;                 // == pw0

    __shared__ __align__(16) unsigned short s_R0[7936];   // 15872B: s_F (phase 1)
    __shared__ float  offv[27][65];                       // 7020B
    __shared__ int2   s_midx[576];                        // 4608B
    __shared__ float4 s_mwgt[576];                        // 9216B

    unsigned short (*s_F)[66][40] = (unsigned short (*)[66][40])s_R0;

    const int lane = tid & 63;
    const int wave = tid >> 6;
    const int kg = lane >> 4, pn = lane & 15;

    // ================= phase 1: offset conv (f16 MFMA, featT staging) =======
    {
        const unsigned short* fT = featT;   // [b][y][x][c] f16
        f32x4 acc[2];
        acc[0] = (f32x4){0.f, 0.f, 0.f, 0.f};
        acc[1] = (f32x4){0.f, 0.f, 0.f, 0.f};

        const int me = tid >> 2;      // main px 0..63 (tile-x me+1)
        const int mg = tid & 3;       // ch-group of 8

        for (int cb = 0; cb < 4; ++cb) {
            if (cb) __syncthreads();       // taps of cb-1 done reading s_F

            // main tile: 3 rows x 64 px x 32 ch, one h8 copy per thread per row
#pragma unroll
            for (int r = 0; r < 3; ++r) {
                int y = h + r - 1;
                h8 d{};
                if ((unsigned)y < (unsigned)H_)
                    d = *(const h8*)(fT + (((size_t)(b * H_ + y) * W_ + (w0 + me)) * CIN_
                                           + (cb << 5) + (mg << 3)));
                *(h8*)&s_F[r][me + 1][mg << 3] = d;
            }
            // halo px: tile-x 0 (x=w0-1) and 65 (x=w0+64), 24 items
            if (tid < 24) {
                int r = tid >> 3, side = (tid >> 2) & 1, g = tid & 3;
                int x = side ? (w0 + 64) : (w0 - 1);
                int t = side ? 65 : 0;
                int y = h + r - 1;
                h8 d{};
                if (((unsigned)y < (unsigned)H_) & ((unsigned)x < (unsigned)W_))
                    d = *(const h8*)(fT + (((size_t)(b * H_ + y) * W_ + x) * CIN_
                                           + (cb << 5) + (g << 3)));
                *(h8*)&s_F[r][t][g << 3] = d;
            }
            __syncthreads();

            const int qb2 = cb * 18;
            const h8* wb = (const h8*)woff_swz;
            h8 a0 = wb[(size_t)(qb2    ) * 64 + lane];
            h8 a1 = wb[(size_t)(qb2 + 1) * 64 + lane];
#pragma unroll
            for (int k = 0; k < 9; ++k) {
                const int ky = k / 3, kx = k - 3 * ky;
                h8 bfr = *(const h8*)&s_F[ky][wave * 16 + pn + kx][kg * 8];
                h8 na0, na1;
                if (k < 8) {
                    na0 = wb[(size_t)(qb2 + 2 * k + 2) * 64 + lane];
                    na1 = wb[(size_t)(qb2 + 2 * k + 3) * 64 + lane];
                }
                acc[0] = __builtin_amdgcn_mfma_f32_16x16x32_f16(a0, bfr, acc[0], 0, 0, 0);
                acc[1] = __builtin_amdgcn_mfma_f32_16x16x32_f16(a1, bfr, acc[1], 0, 0, 0);
                if (k < 8) { a0 = na0; a1 = na1; }
            }
        }

        // epilogue -> offv (LDS, f32)
        const int row0 = kg << 2;
        const int pwl  = wave * 16 + pn;
#pragma unroll
        for (int mt = 0; mt < 2; ++mt) {
#pragma unroll
            for (int i = 0; i < 4; ++i) {
                int oc = mt * 16 + row0 + i;
                if (oc < 27) {
                    float v = acc[mt][i] + b_off[oc];
                    if (oc >= 18) v = 1.f / (1.f + __expf(-v));
                    offv[oc][pwl] = v;
                }
            }
        }
    }
    __syncthreads();   // offv visible to all

    // ================= bilinear metadata: 9 taps x 64 px =================
    for (int i = tid; i < 576; i += 256) {
        int k = i >> 6, p = i & 63;
        int ky = k / 3, kx = k - ky * 3;
        int pw = w0 + p;
        float offy = offv[2 * k    ][p];
        float offx = offv[2 * k + 1][p];
        float mask = offv[18 + k   ][p];
        float py  = offy + (float)(h  + ky - 1);
        float px_ = offx + (float)(pw + kx - 1);
        float y0f = floorf(py), x0f = floorf(px_);
        float ly = py - y0f, lx = px_ - x0f;
        int y0 = (int)y0f, x0 = (int)x0f;
        int y1 = y0 + 1;
        int hx = min(max(x0, 0), W_ - 2);
        float wlo = 0.f, whi = 0.f;
        if (x0 == hx)          { wlo = 1.f - lx; whi = lx; }     // normal
        else if (x0 == hx - 1) { wlo = lx; }                     // x0 == -1
        else if (x0 == hx + 1) { whi = 1.f - lx; }               // x0 == W-1
        float wt_top = ((unsigned)y0 < (unsigned)H_) ? (1.f - ly) * mask : 0.f;
        float wt_bot = ((unsigned)y1 < (unsigned)H_) ? ly * mask : 0.f;
        int cy0 = min(max(y0, 0), H_ - 1), cy1 = min(max(y1, 0), H_ - 1);
        s_midx[i] = make_int2(cy0 * W_ + hx, cy1 * W_ + hx);
        s_mwgt[i] = make_float4(wt_top * wlo, wt_top * whi,
                                wt_bot * wlo, wt_bot * whi);
    }
    __syncthreads();   // meta visible (last barrier in the kernel)

    // ========== phase 2: deformable conv, register-direct B-frags ==========
    const int p = wave * 16 + pn;         // this lane's pixel (0..63)
    const char* inpTb = (const char*)(inpT + (size_t)b * CIN_ * HW_);

    f32x4 acc2[8];
#pragma unroll
    for (int m = 0; m < 8; ++m) acc2[m] = (f32x4){0.f, 0.f, 0.f, 0.f};

    h8 pf0, pf1, pf2, pf3;   // corners: (y0,x0),(y0,x1),(y1,x0),(y1,x1)

    auto issue = [&](int qq) {
        int cbq = qq / 9;
        int k   = qq - cbq * 9;
        int2 id = s_midx[(k << 6) + p];
        int coff = (cbq << 6) + (kg << 4);   // byte: (cbq*32 + kg*8) f16
        const char* g0 = inpTb + ((size_t)(unsigned)id.x << 8) + coff;
        const char* g1 = inpTb + ((size_t)(unsigned)id.y << 8) + coff;
        pf0 = *(const h8*)(g0);
        pf1 = *(const h8*)(g0 + 256);     // x+1: +CIN_*2B
        pf2 = *(const h8*)(g1);
        pf3 = *(const h8*)(g1 + 256);
    };

    // prologue: gathers(0) first, then A(0) behind them
    issue(0);
    h8 af[8];
    {
        const h8* wp = (const h8*)w_swz + lane;
#pragma unroll
        for (int m = 0; m < 8; ++m) af[m] = wp[(size_t)m * 64];
    }

    for (int q = 0; q < 36; ++q) {
        int k = q - (q / 9) * 9;

        // combine pf(q) -> B-frag. Wait: vmcnt(8) (A(q) trails the gathers).
        float4 wt = s_mwgt[(k << 6) + p];
        h8 v = pf0 * (_Float16)wt.x;
        v += pf1 * (_Float16)wt.y;
        v += pf2 * (_Float16)wt.z;
        v += pf3 * (_Float16)wt.w;

        int qn = (q + 1 < 36) ? q + 1 : 35;
        issue(qn);                         // gathers(q+1) in flight

        // MFMAs on A(q): wait vmcnt(4) — A(q) loaded last iter, long done.
#pragma unroll
        for (int m = 0; m < 8; ++m)
            acc2[m] = __builtin_amdgcn_mfma_f32_16x16x32_f16(af[m], v, acc2[m], 0, 0, 0);

        // A(q+1) for next iter (af regs die above, reborn here: +32 VGPR peak)
        const h8* wpn = (const h8*)w_swz + (size_t)(qn * 8) * 64 + lane;
#pragma unroll
        for (int m = 0; m < 8; ++m) af[m] = wpn[(size_t)m * 64];
    }

    // epilogue: D[row=oc_local][col=px_local]; col = pn, row = kg*4+i
    const int pw = w0 + wave * 16 + pn;
#pragma unroll
    for (int m = 0; m < 8; ++m) {
#pragma unroll
        for (int i = 0; i < 4; ++i) {
            int oc = m * 16 + (kg << 2) + i;
            out[((size_t)(b * COUT_ + oc)) * HW_ + h * W_ + pw] =
                acc2[m][i] + b_dc[oc];
        }
    }
}

extern "C" void kernel_launch(void* const* d_in, const int* in_sizes, int n_in,
                              void* d_out, int out_size, void* d_ws, size_t ws_size,
                              hipStream_t stream)
{
    const float* inp   = (const float*)d_in[0];
    const float* feat  = (const float*)d_in[1];
    const float* w_off = (const float*)d_in[2];
    const float* b_off = (const float*)d_in[3];
    const float* w_dc  = (const float*)d_in[4];
    const float* b_dc  = (const float*)d_in[5];
    float* out  = (float*)d_out;
    unsigned short* w_swz    = (unsigned short*)d_ws;                        // 288 KB (f16)
    unsigned short* woff_swz = (unsigned short*)((char*)d_ws + 294912);      // 72 KB (f16)
    unsigned short* inpT     = (unsigned short*)((char*)d_ws + 368640);      // 16 MB (f16 NHWC)
    unsigned short* featT    = (unsigned short*)((char*)d_ws + 368640 + 16777216);  // 16 MB

    prep_kernel<<<dim3(1114), dim3(256), 0, stream>>>(inp, feat, w_dc, w_off,
                                                      inpT, featT, w_swz, woff_swz);
    fused_kernel<<<dim3(1024), dim3(256), 0, stream>>>(featT, inpT, woff_swz, w_swz,
                                                       b_off, b_dc, out);
}

// Round 12
// 211.186 us; speedup vs baseline: 1.0317x; 1.0285x over previous
//
#include <hip/hip_runtime.h>
#include <math.h>

#define B_    4
#define CIN_  128
#define COUT_ 128
#define H_    128
#define W_    128
#define HW_   (H_*W_)
#define KK_   9

typedef __attribute__((ext_vector_type(4))) float f32x4;
typedef _Float16 h8 __attribute__((ext_vector_type(8)));
typedef float f2v __attribute__((ext_vector_type(2), aligned(4)));  // 4B-aligned pair load

static __device__ __forceinline__ unsigned short f2h(float f) {
    union { _Float16 h; unsigned short u; } v; v.h = (_Float16)f;
    return v.u;
}

// K-chunk order (both GEMMs): q = cblock*9 + tap (channel-outer, tap inner).

// ---------------------------------------------------------------------------
// Prep (fused): bx<1024 -> transpose {inp,feat} NCHW f32 -> NHWC f16;
//               bx<1096 -> w_dc swizzle (f16); else -> w_off swizzle (f16).
// ---------------------------------------------------------------------------
__global__ __launch_bounds__(256) void prep_kernel(
    const float* __restrict__ inp, const float* __restrict__ feat,
    const float* __restrict__ w_dc, const float* __restrict__ w_off,
    unsigned short* __restrict__ inpT, unsigned short* __restrict__ featT,
    unsigned short* __restrict__ w_swz, unsigned short* __restrict__ woff_swz)
{
    const int bx = blockIdx.x;
    const int tid = threadIdx.x;
    __shared__ unsigned short s_T[128 * 142];   // 36352 B (tpose branch only)

    if (bx < 1024) {
        // ---- transpose: block = (src, b, y); LDS tile [128x][142c] ----
        const int bi = bx & 511;
        const int b = bi >> 7, y = bi & 127;
        const float* src = (bx < 512 ? inp : feat) + (size_t)b * CIN_ * HW_ + y * W_;
        unsigned short* dstb = (bx < 512 ? inpT : featT) + (size_t)bi * (W_ * CIN_);
        const int xs = (tid & 63) * 2;
        const int c0 = tid >> 6;
#pragma unroll 4
        for (int p = 0; p < 32; ++p) {
            int c = c0 + 4 * p;
            f2v d = *(const f2v*)(src + (size_t)c * HW_ + xs);
            s_T[xs * 142 + c]       = f2h(d.x);
            s_T[(xs + 1) * 142 + c] = f2h(d.y);
        }
        __syncthreads();
        const int cs = (tid & 15) * 8;
        const int x0 = tid >> 4;
#pragma unroll
        for (int p = 0; p < 8; ++p) {
            int x = x0 + 16 * p;
            unsigned r[4];
#pragma unroll
            for (int j = 0; j < 4; ++j) {
                unsigned lo = s_T[x * 142 + cs + 2 * j];
                unsigned hi = s_T[x * 142 + cs + 2 * j + 1];
                r[j] = lo | (hi << 16);
            }
            *(int4*)(dstb + (size_t)x * CIN_ + cs) = make_int4(r[0], r[1], r[2], r[3]);
        }
    } else if (bx < 1096) {
        // ---- w_dc swizzle -> f16 A-fragments ----
        int idx = (bx - 1024) * 256 + tid;   // [0, 36*8*64)
        int q   = idx >> 9;
        int rem = idx & 511;
        int ocb = rem >> 6;
        int l   = rem & 63;
        int cbq = q / 9;
        int k   = q - cbq * 9;
        int cb  = (cbq << 5) + ((l >> 4) << 3);
        int oc  = (ocb << 4) + (l & 15);
        unsigned r[4];
#pragma unroll
        for (int j = 0; j < 4; ++j) {
            float f0 = w_dc[((size_t)(oc * CIN_ + cb + 2 * j    )) * KK_ + k];
            float f1 = w_dc[((size_t)(oc * CIN_ + cb + 2 * j + 1)) * KK_ + k];
            r[j] = (unsigned)f2h(f0) | ((unsigned)f2h(f1) << 16);
        }
        *(int4*)&w_swz[(size_t)idx * 8] = make_int4(r[0], r[1], r[2], r[3]);
    } else {
        // ---- w_off swizzle -> f16 A-fragments, oc padded 27->32 ----
        int idx = (bx - 1096) * 256 + tid;   // [0, 36*2*64)
        int q   = idx >> 7;
        int rem = idx & 127;
        int l   = rem & 63;
        int cbq = q / 9;
        int k   = q - cbq * 9;
        int cb  = (cbq << 5) + ((l >> 4) << 3);
        int oc  = ((rem >> 6) << 4) + (l & 15);
        unsigned r[4];
#pragma unroll
        for (int j = 0; j < 4; ++j) {
            float f0 = 0.f, f1 = 0.f;
            if (oc < 27) {
                f0 = w_off[((size_t)(oc * CIN_ + cb + 2 * j    )) * KK_ + k];
                f1 = w_off[((size_t)(oc * CIN_ + cb + 2 * j + 1)) * KK_ + k];
            }
            r[j] = (unsigned)f2h(f0) | ((unsigned)f2h(f1) << 16);
        }
        *(int4*)&woff_swz[(size_t)idx * 8] = make_int4(r[0], r[1], r[2], r[3]);
    }
}

// ---------------------------------------------------------------------------
// Fused main (v10):
// Phase 1: offset conv from featT (NHWC f16), LDS halo tile, f16 MFMA
//   (unchanged from v7).
// Phase 2: REVERT to v7's measured-best structure (wave owns 32-oc slice x
//   64 px; B via double-buffered LDS; lgkm-only raw barrier; A-frags
//   prefetched 1 iter ahead). v8/v9 root cause: register-direct B made every
//   wave load all 8 A-frags (12 VMEM/thread/chunk vs v7's 6) on the
//   VMEM-issue-bound pipe -> 1.84x slower. Refinements on v7:
//   (a) k-outer/cbq-inner loop: the 4 channel-blocks of a tap share
//       s_midx/s_mwgt and gather base addresses -> hoisted per tap; 3/4 of
//       chunks gather at base+imm (offsets <=448, 13-bit imm) with zero
//       address VALU and zero DS reads.
//   (b) s_V row stride 40 -> 44 shorts (22 dwords, gcd 2 vs 32 banks): all
//       16 quads hit distinct bank starts on write AND read (stride-20 had
//       period-8 aliasing).
// ---------------------------------------------------------------------------
__global__ __launch_bounds__(256, 4) void fused_kernel(
    const unsigned short* __restrict__ featT, const unsigned short* __restrict__ inpT,
    const unsigned short* __restrict__ woff_swz, const unsigned short* __restrict__ w_swz,
    const float* __restrict__ b_off, const float* __restrict__ b_dc,
    float* __restrict__ out)
{
    const int tid = threadIdx.x;
    const int bx = blockIdx.x;
    const int lidx = ((bx & 7) << 7) | (bx >> 3);   // XCD swizzle, 1024 blocks
    const int b  = lidx >> 8;
    const int h  = (lidx & 255) >> 1;
    const int w0 = (lidx & 1) << 6;                 // == pw0

    __shared__ __align__(16) unsigned short s_R0[7936];   // 15872B: s_F / s_V
    __shared__ float  offv[27][65];                       // 7020B
    __shared__ int2   s_midx[576];                        // 4608B
    __shared__ float4 s_mwgt[576];                        // 9216B

    unsigned short (*s_F)[66][40] = (unsigned short (*)[66][40])s_R0;   // phase 1
    unsigned short (*s_V)[64][44] = (unsigned short (*)[64][44])s_R0;   // phase 2

    const int lane = tid & 63;
    const int wave = tid >> 6;
    const int kg = lane >> 4, pn = lane & 15;

    // ================= phase 1: offset conv (f16 MFMA, featT staging) =======
    {
        const unsigned short* fT = featT;   // [b][y][x][c] f16
        f32x4 acc[2];
        acc[0] = (f32x4){0.f, 0.f, 0.f, 0.f};
        acc[1] = (f32x4){0.f, 0.f, 0.f, 0.f};

        const int me = tid >> 2;      // main px 0..63 (tile-x me+1)
        const int mg = tid & 3;       // ch-group of 8

        for (int cb = 0; cb < 4; ++cb) {
            if (cb) __syncthreads();       // taps of cb-1 done reading s_F

            // main tile: 3 rows x 64 px x 32 ch, one h8 copy per thread per row
#pragma unroll
            for (int r = 0; r < 3; ++r) {
                int y = h + r - 1;
                h8 d{};
                if ((unsigned)y < (unsigned)H_)
                    d = *(const h8*)(fT + (((size_t)(b * H_ + y) * W_ + (w0 + me)) * CIN_
                                           + (cb << 5) + (mg << 3)));
                *(h8*)&s_F[r][me + 1][mg << 3] = d;
            }
            // halo px: tile-x 0 (x=w0-1) and 65 (x=w0+64), 24 items
            if (tid < 24) {
                int r = tid >> 3, side = (tid >> 2) & 1, g = tid & 3;
                int x = side ? (w0 + 64) : (w0 - 1);
                int t = side ? 65 : 0;
                int y = h + r - 1;
                h8 d{};
                if (((unsigned)y < (unsigned)H_) & ((unsigned)x < (unsigned)W_))
                    d = *(const h8*)(fT + (((size_t)(b * H_ + y) * W_ + x) * CIN_
                                           + (cb << 5) + (g << 3)));
                *(h8*)&s_F[r][t][g << 3] = d;
            }
            __syncthreads();

            const int qb2 = cb * 18;
            const h8* wb = (const h8*)woff_swz;
            h8 a0 = wb[(size_t)(qb2    ) * 64 + lane];
            h8 a1 = wb[(size_t)(qb2 + 1) * 64 + lane];
#pragma unroll
            for (int k = 0; k < 9; ++k) {
                const int ky = k / 3, kx = k - 3 * ky;
                h8 bfr = *(const h8*)&s_F[ky][wave * 16 + pn + kx][kg * 8];
                h8 na0, na1;
                if (k < 8) {
                    na0 = wb[(size_t)(qb2 + 2 * k + 2) * 64 + lane];
                    na1 = wb[(size_t)(qb2 + 2 * k + 3) * 64 + lane];
                }
                acc[0] = __builtin_amdgcn_mfma_f32_16x16x32_f16(a0, bfr, acc[0], 0, 0, 0);
                acc[1] = __builtin_amdgcn_mfma_f32_16x16x32_f16(a1, bfr, acc[1], 0, 0, 0);
                if (k < 8) { a0 = na0; a1 = na1; }
            }
        }

        // epilogue -> offv (LDS, f32)
        const int row0 = kg << 2;
        const int pwl  = wave * 16 + pn;
#pragma unroll
        for (int mt = 0; mt < 2; ++mt) {
#pragma unroll
            for (int i = 0; i < 4; ++i) {
                int oc = mt * 16 + row0 + i;
                if (oc < 27) {
                    float v = acc[mt][i] + b_off[oc];
                    if (oc >= 18) v = 1.f / (1.f + __expf(-v));
                    offv[oc][pwl] = v;
                }
            }
        }
    }
    __syncthreads();   // offv visible to all

    // ================= bilinear metadata: 9 taps x 64 px =================
    for (int i = tid; i < 576; i += 256) {
        int k = i >> 6, p = i & 63;
        int ky = k / 3, kx = k - ky * 3;
        int pw = w0 + p;
        float offy = offv[2 * k    ][p];
        float offx = offv[2 * k + 1][p];
        float mask = offv[18 + k   ][p];
        float py  = offy + (float)(h  + ky - 1);
        float px_ = offx + (float)(pw + kx - 1);
        float y0f = floorf(py), x0f = floorf(px_);
        float ly = py - y0f, lx = px_ - x0f;
        int y0 = (int)y0f, x0 = (int)x0f;
        int y1 = y0 + 1;
        int hx = min(max(x0, 0), W_ - 2);
        float wlo = 0.f, whi = 0.f;
        if (x0 == hx)          { wlo = 1.f - lx; whi = lx; }     // normal
        else if (x0 == hx - 1) { wlo = lx; }                     // x0 == -1
        else if (x0 == hx + 1) { whi = 1.f - lx; }               // x0 == W-1
        float wt_top = ((unsigned)y0 < (unsigned)H_) ? (1.f - ly) * mask : 0.f;
        float wt_bot = ((unsigned)y1 < (unsigned)H_) ? ly * mask : 0.f;
        int cy0 = min(max(y0, 0), H_ - 1), cy1 = min(max(y1, 0), H_ - 1);
        s_midx[i] = make_int2(cy0 * W_ + hx, cy1 * W_ + hx);
        s_mwgt[i] = make_float4(wt_top * wlo, wt_top * whi,
                                wt_bot * wlo, wt_bot * whi);
    }
    __syncthreads();   // meta visible; offv dead; s_R0 reusable as s_V

    // ========== phase 2: deformable conv (f16 MFMA, v7 structure) ==========
    const int px = tid >> 2;              // gather pixel; quad shares a corner
    const int cs = tid & 3;               // channel quarter (8 ch)
    const char* inpTb = (const char*)(inpT + (size_t)b * CIN_ * HW_);

    f32x4 acc2[2][4];
#pragma unroll
    for (int mt = 0; mt < 2; ++mt)
#pragma unroll
        for (int nt = 0; nt < 4; ++nt) acc2[mt][nt] = (f32x4){0.f, 0.f, 0.f, 0.f};

    h8 pf0, pf1, pf2, pf3;   // corners: (y0,x0),(y0,x1),(y1,x0),(y1,x1)

    // k=0 bases + gathers for chunk (k=0, cbq=0)
    int2 id0 = s_midx[px];
    float4 wt = s_mwgt[px];
    const char* g0 = inpTb + ((size_t)(unsigned)id0.x << 8) + (cs << 4);
    const char* g1 = inpTb + ((size_t)(unsigned)id0.y << 8) + (cs << 4);
    pf0 = *(const h8*)(g0);
    pf1 = *(const h8*)(g0 + 256);
    pf2 = *(const h8*)(g1);
    pf3 = *(const h8*)(g1 + 256);

    // A-frags for first chunk q=0 (loaded after gathers: newest behind them)
    h8 af0, af1;
    {
        const h8* wp = (const h8*)w_swz + (size_t)(wave * 2) * 64 + lane;
        af0 = wp[0];
        af1 = wp[64];
    }

    for (int k = 0; k < 9; ++k) {
        // next tap's metadata/bases (consumed at cbq==3; 2 DS reads per 4 chunks)
        const int kn = (k + 1 < 9) ? k + 1 : 8;
        int2 idn = s_midx[(kn << 6) + px];
        float4 wtn = s_mwgt[(kn << 6) + px];
        const char* g0n = inpTb + ((size_t)(unsigned)idn.x << 8) + (cs << 4);
        const char* g1n = inpTb + ((size_t)(unsigned)idn.y << 8) + (cs << 4);

#pragma unroll
        for (int cbq = 0; cbq < 4; ++cbq) {
            // combine pf (chunk (k,cbq)) -> B-fragment
            h8 v = pf0 * (_Float16)wt.x;
            v += pf1 * (_Float16)wt.y;
            v += pf2 * (_Float16)wt.z;
            v += pf3 * (_Float16)wt.w;

            const int par = cbq & 1;      // flat index 4k+cbq -> parity cbq&1
            *(h8*)&s_V[par][px][cs << 3] = v;

            // issue next chunk's gathers (imm-offset within tap; new bases at k-edge)
            if (cbq < 3) {
                const int off = (cbq + 1) << 6;
                pf0 = *(const h8*)(g0 + off);
                pf1 = *(const h8*)(g0 + 256 + off);
                pf2 = *(const h8*)(g1 + off);
                pf3 = *(const h8*)(g1 + 256 + off);
            } else {
                pf0 = *(const h8*)(g0n);
                pf1 = *(const h8*)(g0n + 256);
                pf2 = *(const h8*)(g1n);
                pf3 = *(const h8*)(g1n + 256);
            }

            // A-frags for next chunk (newest in queue; consumed next iter)
            const int qn = (cbq < 3) ? (cbq + 1) * 9 + k : kn;
            const h8* wpn = (const h8*)w_swz + (size_t)(qn * 8 + wave * 2) * 64 + lane;
            h8 na0 = wpn[0];
            h8 na1 = wpn[64];

            // lgkm-only barrier: ds_write visible; global loads stay in flight
            asm volatile("s_waitcnt lgkmcnt(0)" ::: "memory");
            __builtin_amdgcn_s_barrier();
            __builtin_amdgcn_sched_barrier(0);

#pragma unroll
            for (int nt = 0; nt < 4; ++nt) {
                h8 bfr = *(const h8*)&s_V[par][nt * 16 + pn][kg * 8];
                acc2[0][nt] = __builtin_amdgcn_mfma_f32_16x16x32_f16(af0, bfr, acc2[0][nt], 0, 0, 0);
                acc2[1][nt] = __builtin_amdgcn_mfma_f32_16x16x32_f16(af1, bfr, acc2[1][nt], 0, 0, 0);
            }
            af0 = na0; af1 = na1;
        }
        g0 = g0n; g1 = g1n; wt = wtn;
    }

    const int row0 = (lane >> 4) << 2;
    const int col  = lane & 15;
#pragma unroll
    for (int mt = 0; mt < 2; ++mt) {
#pragma unroll
        for (int nt = 0; nt < 4; ++nt) {
            int pw = w0 + nt * 16 + col;
#pragma unroll
            for (int i = 0; i < 4; ++i) {
                int oc = wave * 32 + mt * 16 + row0 + i;
                out[((size_t)(b * COUT_ + oc)) * HW_ + h * W_ + pw] =
                    acc2[mt][nt][i] + b_dc[oc];
            }
        }
    }
}

extern "C" void kernel_launch(void* const* d_in, const int* in_sizes, int n_in,
                              void* d_out, int out_size, void* d_ws, size_t ws_size,
                              hipStream_t stream)
{
    const float* inp   = (const float*)d_in[0];
    const float* feat  = (const float*)d_in[1];
    const float* w_off = (const float*)d_in[2];
    const float* b_off = (const float*)d_in[3];
    const float* w_dc  = (const float*)d_in[4];
    const float* b_dc  = (const float*)d_in[5];
    float* out  = (float*)d_out;
    unsigned short* w_swz    = (unsigned short*)d_ws;                        // 288 KB (f16)
    unsigned short* woff_swz = (unsigned short*)((char*)d_ws + 294912);      // 72 KB (f16)
    unsigned short* inpT     = (unsigned short*)((char*)d_ws + 368640);      // 16 MB (f16 NHWC)
    unsigned short* featT    = (unsigned short*)((char*)d_ws + 368640 + 16777216);  // 16 MB

    prep_kernel<<<dim3(1114), dim3(256), 0, stream>>>(inp, feat, w_dc, w_off,
                                                      inpT, featT, w_swz, woff_swz);
    fused_kernel<<<dim3(1024), dim3(256), 0, stream>>>(featT, inpT, woff_swz, w_swz,
                                                       b_off, b_dc, out);
}

// Round 13
// 163.495 us; speedup vs baseline: 1.3327x; 1.2917x over previous
//
#include <hip/hip_runtime.h>
#include <math.h>

#define B_    4
#define CIN_  128
#define COUT_ 128
#define H_    128
#define W_    128
#define HW_   (H_*W_)
#define KK_   9

typedef __attribute__((ext_vector_type(4))) float f32x4;
typedef _Float16 h8 __attribute__((ext_vector_type(8)));
typedef float f2v __attribute__((ext_vector_type(2), aligned(4)));  // 4B-aligned pair load

static __device__ __forceinline__ unsigned short f2h(float f) {
    union { _Float16 h; unsigned short u; } v; v.h = (_Float16)f;
    return v.u;
}

// K-chunk order (both GEMMs): q = cblock*9 + tap (channel-outer, tap inner).

// ---------------------------------------------------------------------------
// Prep (fused): bx<1024 -> transpose {inp,feat} NCHW f32 -> NHWC f16;
//               bx<1096 -> w_dc swizzle (f16); else -> w_off swizzle (f16).
// ---------------------------------------------------------------------------
__global__ __launch_bounds__(256) void prep_kernel(
    const float* __restrict__ inp, const float* __restrict__ feat,
    const float* __restrict__ w_dc, const float* __restrict__ w_off,
    unsigned short* __restrict__ inpT, unsigned short* __restrict__ featT,
    unsigned short* __restrict__ w_swz, unsigned short* __restrict__ woff_swz)
{
    const int bx = blockIdx.x;
    const int tid = threadIdx.x;
    __shared__ unsigned short s_T[128 * 142];   // 36352 B (tpose branch only)

    if (bx < 1024) {
        // ---- transpose: block = (src, b, y); LDS tile [128x][142c] ----
        const int bi = bx & 511;
        const int b = bi >> 7, y = bi & 127;
        const float* src = (bx < 512 ? inp : feat) + (size_t)b * CIN_ * HW_ + y * W_;
        unsigned short* dstb = (bx < 512 ? inpT : featT) + (size_t)bi * (W_ * CIN_);
        const int xs = (tid & 63) * 2;
        const int c0 = tid >> 6;
#pragma unroll 4
        for (int p = 0; p < 32; ++p) {
            int c = c0 + 4 * p;
            f2v d = *(const f2v*)(src + (size_t)c * HW_ + xs);
            s_T[xs * 142 + c]       = f2h(d.x);
            s_T[(xs + 1) * 142 + c] = f2h(d.y);
        }
        __syncthreads();
        const int cs = (tid & 15) * 8;
        const int x0 = tid >> 4;
#pragma unroll
        for (int p = 0; p < 8; ++p) {
            int x = x0 + 16 * p;
            unsigned r[4];
#pragma unroll
            for (int j = 0; j < 4; ++j) {
                unsigned lo = s_T[x * 142 + cs + 2 * j];
                unsigned hi = s_T[x * 142 + cs + 2 * j + 1];
                r[j] = lo | (hi << 16);
            }
            *(int4*)(dstb + (size_t)x * CIN_ + cs) = make_int4(r[0], r[1], r[2], r[3]);
        }
    } else if (bx < 1096) {
        // ---- w_dc swizzle -> f16 A-fragments ----
        int idx = (bx - 1024) * 256 + tid;   // [0, 36*8*64)
        int q   = idx >> 9;
        int rem = idx & 511;
        int ocb = rem >> 6;
        int l   = rem & 63;
        int cbq = q / 9;
        int k   = q - cbq * 9;
        int cb  = (cbq << 5) + ((l >> 4) << 3);
        int oc  = (ocb << 4) + (l & 15);
        unsigned r[4];
#pragma unroll
        for (int j = 0; j < 4; ++j) {
            float f0 = w_dc[((size_t)(oc * CIN_ + cb + 2 * j    )) * KK_ + k];
            float f1 = w_dc[((size_t)(oc * CIN_ + cb + 2 * j + 1)) * KK_ + k];
            r[j] = (unsigned)f2h(f0) | ((unsigned)f2h(f1) << 16);
        }
        *(int4*)&w_swz[(size_t)idx * 8] = make_int4(r[0], r[1], r[2], r[3]);
    } else {
        // ---- w_off swizzle -> f16 A-fragments, oc padded 27->32 ----
        int idx = (bx - 1096) * 256 + tid;   // [0, 36*2*64)
        int q   = idx >> 7;
        int rem = idx & 127;
        int l   = rem & 63;
        int cbq = q / 9;
        int k   = q - cbq * 9;
        int cb  = (cbq << 5) + ((l >> 4) << 3);
        int oc  = ((rem >> 6) << 4) + (l & 15);
        unsigned r[4];
#pragma unroll
        for (int j = 0; j < 4; ++j) {
            float f0 = 0.f, f1 = 0.f;
            if (oc < 27) {
                f0 = w_off[((size_t)(oc * CIN_ + cb + 2 * j    )) * KK_ + k];
                f1 = w_off[((size_t)(oc * CIN_ + cb + 2 * j + 1)) * KK_ + k];
            }
            r[j] = (unsigned)f2h(f0) | ((unsigned)f2h(f1) << 16);
        }
        *(int4*)&woff_swz[(size_t)idx * 8] = make_int4(r[0], r[1], r[2], r[3]);
    }
}

// ---------------------------------------------------------------------------
// Fused main (v11): byte-identical to v7 (the measured best, fused=63us)
// except ONE change in phase 2: the bilinear gather prefetch is TWO chunks
// deep (named slots A/B, loop unrolled x2 — all indices static). v7's
// residual was ~260 cy/chunk ~= one L2 gather round-trip: 1-deep prefetch
// (issued mid-iter t, consumed top of t+1) left the latency exposed. 2-deep
// gives each gather ~2 barrier periods of cover. v10's k-outer restructure
// (anomalous +32MB HBM writes, 105us) is abandoned.
// ---------------------------------------------------------------------------
__global__ __launch_bounds__(256, 4) void fused_kernel(
    const unsigned short* __restrict__ featT, const unsigned short* __restrict__ inpT,
    const unsigned short* __restrict__ woff_swz, const unsigned short* __restrict__ w_swz,
    const float* __restrict__ b_off, const float* __restrict__ b_dc,
    float* __restrict__ out)
{
    const int tid = threadIdx.x;
    const int bx = blockIdx.x;
    const int lidx = ((bx & 7) << 7) | (bx >> 3);   // XCD swizzle, 1024 blocks
    const int b  = lidx >> 8;
    const int h  = (lidx & 255) >> 1;
    const int w0 = (lidx & 1) << 6;                 // == pw0

    __shared__ __align__(16) unsigned short s_R0[7936];   // 15872B: s_F / s_V
    __shared__ float  offv[27][65];                       // 7020B
    __shared__ int2   s_midx[576];                        // 4608B
    __shared__ float4 s_mwgt[576];                        // 9216B

    unsigned short (*s_F)[66][40] = (unsigned short (*)[66][40])s_R0;   // phase 1
    unsigned short (*s_V)[64][40] = (unsigned short (*)[64][40])s_R0;   // phase 2

    const int lane = tid & 63;
    const int wave = tid >> 6;
    const int kg = lane >> 4, pn = lane & 15;

    // ================= phase 1: offset conv (f16 MFMA, featT staging) =======
    {
        const unsigned short* fT = featT;   // [b][y][x][c] f16
        f32x4 acc[2];
        acc[0] = (f32x4){0.f, 0.f, 0.f, 0.f};
        acc[1] = (f32x4){0.f, 0.f, 0.f, 0.f};

        const int me = tid >> 2;      // main px 0..63 (tile-x me+1)
        const int mg = tid & 3;       // ch-group of 8

        for (int cb = 0; cb < 4; ++cb) {
            if (cb) __syncthreads();       // taps of cb-1 done reading s_F

            // main tile: 3 rows x 64 px x 32 ch, one h8 copy per thread per row
#pragma unroll
            for (int r = 0; r < 3; ++r) {
                int y = h + r - 1;
                h8 d{};
                if ((unsigned)y < (unsigned)H_)
                    d = *(const h8*)(fT + (((size_t)(b * H_ + y) * W_ + (w0 + me)) * CIN_
                                           + (cb << 5) + (mg << 3)));
                *(h8*)&s_F[r][me + 1][mg << 3] = d;
            }
            // halo px: tile-x 0 (x=w0-1) and 65 (x=w0+64), 24 items
            if (tid < 24) {
                int r = tid >> 3, side = (tid >> 2) & 1, g = tid & 3;
                int x = side ? (w0 + 64) : (w0 - 1);
                int t = side ? 65 : 0;
                int y = h + r - 1;
                h8 d{};
                if (((unsigned)y < (unsigned)H_) & ((unsigned)x < (unsigned)W_))
                    d = *(const h8*)(fT + (((size_t)(b * H_ + y) * W_ + x) * CIN_
                                           + (cb << 5) + (g << 3)));
                *(h8*)&s_F[r][t][g << 3] = d;
            }
            __syncthreads();

            const int qb2 = cb * 18;
            const h8* wb = (const h8*)woff_swz;
            h8 a0 = wb[(size_t)(qb2    ) * 64 + lane];
            h8 a1 = wb[(size_t)(qb2 + 1) * 64 + lane];
#pragma unroll
            for (int k = 0; k < 9; ++k) {
                const int ky = k / 3, kx = k - 3 * ky;
                h8 bfr = *(const h8*)&s_F[ky][wave * 16 + pn + kx][kg * 8];
                h8 na0, na1;
                if (k < 8) {
                    na0 = wb[(size_t)(qb2 + 2 * k + 2) * 64 + lane];
                    na1 = wb[(size_t)(qb2 + 2 * k + 3) * 64 + lane];
                }
                acc[0] = __builtin_amdgcn_mfma_f32_16x16x32_f16(a0, bfr, acc[0], 0, 0, 0);
                acc[1] = __builtin_amdgcn_mfma_f32_16x16x32_f16(a1, bfr, acc[1], 0, 0, 0);
                if (k < 8) { a0 = na0; a1 = na1; }
            }
        }

        // epilogue -> offv (LDS, f32)
        const int row0 = (lane >> 4) << 2;
        const int col  = lane & 15;
        const int pwl  = wave * 16 + col;
#pragma unroll
        for (int mt = 0; mt < 2; ++mt) {
#pragma unroll
            for (int i = 0; i < 4; ++i) {
                int oc = mt * 16 + row0 + i;
                if (oc < 27) {
                    float v = acc[mt][i] + b_off[oc];
                    if (oc >= 18) v = 1.f / (1.f + __expf(-v));
                    offv[oc][pwl] = v;
                }
            }
        }
    }
    __syncthreads();   // offv visible to all

    // ================= bilinear metadata: 9 taps x 64 px =================
    for (int i = tid; i < 576; i += 256) {
        int k = i >> 6, p = i & 63;
        int ky = k / 3, kx = k - ky * 3;
        int pw = w0 + p;
        float offy = offv[2 * k    ][p];
        float offx = offv[2 * k + 1][p];
        float mask = offv[18 + k   ][p];
        float py  = offy + (float)(h  + ky - 1);
        float px_ = offx + (float)(pw + kx - 1);
        float y0f = floorf(py), x0f = floorf(px_);
        float ly = py - y0f, lx = px_ - x0f;
        int y0 = (int)y0f, x0 = (int)x0f;
        int y1 = y0 + 1;
        int hx = min(max(x0, 0), W_ - 2);
        float wlo = 0.f, whi = 0.f;
        if (x0 == hx)          { wlo = 1.f - lx; whi = lx; }     // normal
        else if (x0 == hx - 1) { wlo = lx; }                     // x0 == -1
        else if (x0 == hx + 1) { whi = 1.f - lx; }               // x0 == W-1
        float wt_top = ((unsigned)y0 < (unsigned)H_) ? (1.f - ly) * mask : 0.f;
        float wt_bot = ((unsigned)y1 < (unsigned)H_) ? ly * mask : 0.f;
        int cy0 = min(max(y0, 0), H_ - 1), cy1 = min(max(y1, 0), H_ - 1);
        s_midx[i] = make_int2(cy0 * W_ + hx, cy1 * W_ + hx);
        s_mwgt[i] = make_float4(wt_top * wlo, wt_top * whi,
                                wt_bot * wlo, wt_bot * whi);
    }
    __syncthreads();   // meta visible; offv dead; s_R0 reusable as s_V

    // ========== phase 2: deformable conv (f16 MFMA, 2-deep gather pipe) =====
    const int px = tid >> 2;              // gather pixel; quad shares a corner
    const int cs = tid & 3;               // channel quarter (8 ch)
    const char* inpTb = (const char*)(inpT + (size_t)b * CIN_ * HW_);

    f32x4 acc2[2][4];
#pragma unroll
    for (int mt = 0; mt < 2; ++mt)
#pragma unroll
        for (int nt = 0; nt < 4; ++nt) acc2[mt][nt] = (f32x4){0.f, 0.f, 0.f, 0.f};

    // two named gather slots (2-deep pipeline; static indexing only)
    h8 sa0, sa1, sa2, sa3;   // slot A: even chunks
    h8 sb0, sb1, sb2, sb3;   // slot B: odd chunks

#define GADDR(qq, G0, G1)                                                    \
    {   int cbq_ = (qq) / 9;                                                 \
        int k_   = (qq) - cbq_ * 9;                                         \
        int2 id_ = s_midx[(k_ << 6) + px];                                   \
        int coff_ = (cbq_ << 6) + (cs << 4);                                 \
        G0 = inpTb + ((size_t)(unsigned)id_.x << 8) + coff_;                 \
        G1 = inpTb + ((size_t)(unsigned)id_.y << 8) + coff_; }

    // prologue: gathers for chunks 0 (slot A) and 1 (slot B), then A-frags(0)
    {
        const char *g0, *g1;
        GADDR(0, g0, g1);
        sa0 = *(const h8*)(g0); sa1 = *(const h8*)(g0 + 256);
        sa2 = *(const h8*)(g1); sa3 = *(const h8*)(g1 + 256);
        GADDR(1, g0, g1);
        sb0 = *(const h8*)(g0); sb1 = *(const h8*)(g0 + 256);
        sb2 = *(const h8*)(g1); sb3 = *(const h8*)(g1 + 256);
    }
    h8 af0, af1;
    {
        const h8* wp = (const h8*)w_swz + (size_t)(wave * 2) * 64 + lane;
        af0 = wp[0];
        af1 = wp[64];
    }

    for (int qq = 0; qq < 36; qq += 2) {
        // ---------- chunk q = qq (slot A, buffer 0) ----------
        {
            const int q = qq;
            const int k = q - (q / 9) * 9;
            float4 wt = s_mwgt[(k << 6) + px];
            h8 v = sa0 * (_Float16)wt.x;
            v += sa1 * (_Float16)wt.y;
            v += sa2 * (_Float16)wt.z;
            v += sa3 * (_Float16)wt.w;
            *(h8*)&s_V[0][px][cs << 3] = v;

            const int qp = (q + 2 < 36) ? q + 2 : 35;   // refill slot A
            const char *g0, *g1;
            GADDR(qp, g0, g1);
            sa0 = *(const h8*)(g0); sa1 = *(const h8*)(g0 + 256);
            sa2 = *(const h8*)(g1); sa3 = *(const h8*)(g1 + 256);

            const int qn = q + 1;                        // A-frags for next chunk
            const h8* wpn = (const h8*)w_swz + (size_t)(qn * 8 + wave * 2) * 64 + lane;
            h8 na0 = wpn[0];
            h8 na1 = wpn[64];

            asm volatile("s_waitcnt lgkmcnt(0)" ::: "memory");
            __builtin_amdgcn_s_barrier();
            __builtin_amdgcn_sched_barrier(0);

#pragma unroll
            for (int nt = 0; nt < 4; ++nt) {
                h8 bfr = *(const h8*)&s_V[0][nt * 16 + pn][kg * 8];
                acc2[0][nt] = __builtin_amdgcn_mfma_f32_16x16x32_f16(af0, bfr, acc2[0][nt], 0, 0, 0);
                acc2[1][nt] = __builtin_amdgcn_mfma_f32_16x16x32_f16(af1, bfr, acc2[1][nt], 0, 0, 0);
            }
            af0 = na0; af1 = na1;
        }
        // ---------- chunk q = qq+1 (slot B, buffer 1) ----------
        {
            const int q = qq + 1;
            const int k = q - (q / 9) * 9;
            float4 wt = s_mwgt[(k << 6) + px];
            h8 v = sb0 * (_Float16)wt.x;
            v += sb1 * (_Float16)wt.y;
            v += sb2 * (_Float16)wt.z;
            v += sb3 * (_Float16)wt.w;
            *(h8*)&s_V[1][px][cs << 3] = v;

            const int qp = (q + 2 < 36) ? q + 2 : 35;   // refill slot B
            const char *g0, *g1;
            GADDR(qp, g0, g1);
            sb0 = *(const h8*)(g0); sb1 = *(const h8*)(g0 + 256);
            sb2 = *(const h8*)(g1); sb3 = *(const h8*)(g1 + 256);

            const int qn = (q + 1 < 36) ? q + 1 : 35;   // A-frags for next chunk
            const h8* wpn = (const h8*)w_swz + (size_t)(qn * 8 + wave * 2) * 64 + lane;
            h8 na0 = wpn[0];
            h8 na1 = wpn[64];

            asm volatile("s_waitcnt lgkmcnt(0)" ::: "memory");
            __builtin_amdgcn_s_barrier();
            __builtin_amdgcn_sched_barrier(0);

#pragma unroll
            for (int nt = 0; nt < 4; ++nt) {
                h8 bfr = *(const h8*)&s_V[1][nt * 16 + pn][kg * 8];
                acc2[0][nt] = __builtin_amdgcn_mfma_f32_16x16x32_f16(af0, bfr, acc2[0][nt], 0, 0, 0);
                acc2[1][nt] = __builtin_amdgcn_mfma_f32_16x16x32_f16(af1, bfr, acc2[1][nt], 0, 0, 0);
            }
            af0 = na0; af1 = na1;
        }
    }
#undef GADDR

    const int row0 = (lane >> 4) << 2;
    const int col  = lane & 15;
#pragma unroll
    for (int mt = 0; mt < 2; ++mt) {
#pragma unroll
        for (int nt = 0; nt < 4; ++nt) {
            int pw = w0 + nt * 16 + col;
#pragma unroll
            for (int i = 0; i < 4; ++i) {
                int oc = wave * 32 + mt * 16 + row0 + i;
                out[((size_t)(b * COUT_ + oc)) * HW_ + h * W_ + pw] =
                    acc2[mt][nt][i] + b_dc[oc];
            }
        }
    }
}

extern "C" void kernel_launch(void* const* d_in, const int* in_sizes, int n_in,
                              void* d_out, int out_size, void* d_ws, size_t ws_size,
                              hipStream_t stream)
{
    const float* inp   = (const float*)d_in[0];
    const float* feat  = (const float*)d_in[1];
    const float* w_off = (const float*)d_in[2];
    const float* b_off = (const float*)d_in[3];
    const float* w_dc  = (const float*)d_in[4];
    const float* b_dc  = (const float*)d_in[5];
    float* out  = (float*)d_out;
    unsigned short* w_swz    = (unsigned short*)d_ws;                        // 288 KB (f16)
    unsigned short* woff_swz = (unsigned short*)((char*)d_ws + 294912);      // 72 KB (f16)
    unsigned short* inpT     = (unsigned short*)((char*)d_ws + 368640);      // 16 MB (f16 NHWC)
    unsigned short* featT    = (unsigned short*)((char*)d_ws + 368640 + 16777216);  // 16 MB

    prep_kernel<<<dim3(1114), dim3(256), 0, stream>>>(inp, feat, w_dc, w_off,
                                                      inpT, featT, w_swz, woff_swz);
    fused_kernel<<<dim3(1024), dim3(256), 0, stream>>>(featT, inpT, woff_swz, w_swz,
                                                       b_off, b_dc, out);
}